// Round 2
// baseline (669.108 us; speedup 1.0000x reference)
//
#include <hip/hip_runtime.h>
#include <hip/hip_bf16.h>
#include <stdint.h>

// Problem constants
#define BB 8
#define CC 512
#define HH 128
#define WW 128
#define HP 64
#define NN 4096
#define C8 64
#define EPSF 1e-5f

typedef __attribute__((ext_vector_type(8))) short short8;   // 8 bf16 (4 VGPRs)
typedef __attribute__((ext_vector_type(4))) float f32x4;    // MFMA accumulator

__device__ __forceinline__ float bf2f(ushort u) {
    union { uint i; float f; } x; x.i = ((uint)u) << 16; return x.f;
}
__device__ __forceinline__ ushort f2bf(float f) {  // RNE
    uint i = __float_as_uint(f);
    return (ushort)((i + 0x7FFFu + ((i >> 16) & 1u)) >> 16);
}

// ---------------------------------------------------------------------------
// Kernel 1: AvgPool2d(2) + LayerNorm over pooled width (64) -> xn bf16 [B][C][4096]
// one wave per (b,c,h) row; lane = w.  x is f32.
// ---------------------------------------------------------------------------
__global__ __launch_bounds__(256) void pool_ln_kernel(
    const float* __restrict__ x, const float* __restrict__ lw,
    const float* __restrict__ lb, ushort* __restrict__ xn)
{
    int wid = threadIdx.x >> 6, lane = threadIdx.x & 63;
    int row = blockIdx.x * 4 + wid;      // (b*512+c)*64 + h
    int h = row & 63;
    int bc = row >> 6;
    const float* r0 = x + ((size_t)bc * 128 + 2 * h) * 128;
    const float* r1 = r0 + 128;
    float2 a0 = ((const float2*)r0)[lane];
    float2 a1 = ((const float2*)r1)[lane];
    float p = 0.25f * (a0.x + a0.y + a1.x + a1.y);
    float s = p, sq = p * p;
    #pragma unroll
    for (int m = 1; m < 64; m <<= 1) {
        s  += __shfl_xor(s,  m, 64);
        sq += __shfl_xor(sq, m, 64);
    }
    float mu  = s * (1.f / 64.f);
    float var = sq * (1.f / 64.f) - mu * mu;
    float inv = rsqrtf(var + EPSF);
    float v = (p - mu) * inv * lw[lane] + lb[lane];
    xn[(size_t)bc * NN + h * 64 + lane] = f2bf(v);
}

// ---------------------------------------------------------------------------
// Kernel 2: QKV projection GEMM.  Out[o][n] = sum_c W[o][c]*xn[c][n] + bias[o]
// W/bias f32; xn bf16; out bf16.  Block tile 64x64, BK=32, 4 waves (2x2),
// MFMA 16x16x32 bf16.  mt: 0=q, 1=k, 2..9=v chunks.
// ---------------------------------------------------------------------------
__global__ __launch_bounds__(256) void qkv_kernel(
    const ushort* __restrict__ xn,
    const float* __restrict__ wq, const float* __restrict__ bq,
    const float* __restrict__ wk, const float* __restrict__ bk,
    const float* __restrict__ wv, const float* __restrict__ bv,
    ushort* __restrict__ qo, ushort* __restrict__ ko, ushort* __restrict__ vo)
{
    __shared__ __align__(16) ushort As[64][40];   // [o_local][c_local]
    __shared__ __align__(16) ushort Bs[64][66];   // [n_local][c_local] transposed
    int b = blockIdx.z, mt = blockIdx.y;
    int n0 = blockIdx.x * 64;
    const float* W; const float* bias; ushort* outp;
    if (mt == 0)      { W = wq;                              bias = bq;              outp = qo + (size_t)b * C8 * NN; }
    else if (mt == 1) { W = wk;                              bias = bk;              outp = ko + (size_t)b * C8 * NN; }
    else              { W = wv + (size_t)(mt - 2) * 64 * 512; bias = bv + (mt - 2) * 64;
                        outp = vo + (size_t)b * CC * NN + (size_t)(mt - 2) * 64 * NN; }
    const ushort* xb = xn + (size_t)b * CC * NN;
    int t = threadIdx.x;
    int lane = t & 63, wid = t >> 6;
    int wm = wid >> 1, wn = wid & 1;
    f32x4 acc[2][2] = {};

    for (int kc = 0; kc < 512; kc += 32) {
        { // stage A: f32 -> bf16 convert
            int row = t >> 2, k8 = (t & 3) * 8;
            const float* wp_ = &W[row * 512 + kc + k8];
            float4 f0 = *(const float4*)wp_;
            float4 f1 = *(const float4*)(wp_ + 4);
            ushort tmp[8] = { f2bf(f0.x), f2bf(f0.y), f2bf(f0.z), f2bf(f0.w),
                              f2bf(f1.x), f2bf(f1.y), f2bf(f1.z), f2bf(f1.w) };
            *(uint4*)&As[row][k8] = *(const uint4*)tmp;
        }
        { // stage B transposed (bf16 scatter; stride 66 keeps conflicts ~4-way)
            int c = t >> 3, n8 = (t & 7) * 8;
            uint4 v = *(const uint4*)&xb[(size_t)(kc + c) * NN + n0 + n8];
            const ushort* pv = (const ushort*)&v;
            #pragma unroll
            for (int e = 0; e < 8; e++) Bs[n8 + e][c] = pv[e];
        }
        __syncthreads();
        short8 a[2];
        #pragma unroll
        for (int fm = 0; fm < 2; fm++)
            a[fm] = *(const short8*)&As[wm * 32 + fm * 16 + (lane & 15)][(lane >> 4) * 8];
        short8 bb[2];
        #pragma unroll
        for (int fn = 0; fn < 2; fn++) {
            int col = wn * 32 + fn * 16 + (lane & 15);
            union { short8 v; uint u[4]; } bu;
            int c0 = (lane >> 4) * 8;
            #pragma unroll
            for (int p = 0; p < 4; p++)
                bu.u[p] = *(const uint*)&Bs[col][c0 + 2 * p];
            bb[fn] = bu.v;
        }
        #pragma unroll
        for (int fm = 0; fm < 2; fm++)
            #pragma unroll
            for (int fn = 0; fn < 2; fn++)
                acc[fm][fn] = __builtin_amdgcn_mfma_f32_16x16x32_bf16(a[fm], bb[fn], acc[fm][fn], 0, 0, 0);
        __syncthreads();
    }
    #pragma unroll
    for (int fm = 0; fm < 2; fm++) {
        #pragma unroll
        for (int fn = 0; fn < 2; fn++) {
            int col = n0 + wn * 32 + fn * 16 + (lane & 15);
            #pragma unroll
            for (int r = 0; r < 4; r++) {
                int orow = wm * 32 + fm * 16 + (lane >> 4) * 4 + r;
                outp[(size_t)orow * NN + col] = f2bf(acc[fm][fn][r] + bias[orow]);
            }
        }
    }
}

// ---------------------------------------------------------------------------
// Kernel 3: fused flash attention + out-LN + 2x nearest upsample + residual.
// One block per (b, h): n-tile = 64 = one LN row per channel.
// 8 waves; wave owns a 64-channel V/O chunk. Online softmax in LDS.
// q/k/v bf16 from ws; x residual, gamma, LN params, out all f32.
// ---------------------------------------------------------------------------
__global__ __launch_bounds__(512) void attn_kernel(
    const ushort* __restrict__ qg, const ushort* __restrict__ kg,
    const ushort* __restrict__ vg, const float* __restrict__ x,
    const float* __restrict__ gamma_p,
    const float* __restrict__ lnw_g, const float* __restrict__ lnb_g,
    float* __restrict__ out)
{
    __shared__ __align__(16) ushort Qs[64][66];  // [n][c] transposed
    __shared__ __align__(16) ushort Ks[64][66];  // [m][c] transposed
    __shared__ __align__(16) float  Ss[64][65];  // scores [n][m]
    __shared__ __align__(16) ushort Ps[64][72];  // P bf16 [n][m]
    __shared__ float row_m[64], row_l[64], row_scale[64];
    __shared__ float lnw[64], lnb[64];

    int bid = blockIdx.x;
    int b = bid & 7;          // batch = bid%8 -> one batch per XCD (L2 locality for K/V)
    int h = bid >> 3;
    int t = threadIdx.x, wid = t >> 6, lane = t & 63;
    const ushort* qb = qg + (size_t)b * C8 * NN;
    const ushort* kb = kg + (size_t)b * C8 * NN;
    const ushort* vb = vg + (size_t)b * CC * NN;

    if (t < 64) {
        row_m[t] = -1e30f; row_l[t] = 0.f;
        lnw[t] = lnw_g[t]; lnb[t] = lnb_g[t];
    }
    { // stage Q tile (transposed)
        int c = t >> 3, n8 = (t & 7) * 8;
        uint4 v = *(const uint4*)&qb[(size_t)c * NN + h * 64 + n8];
        const ushort* pv = (const ushort*)&v;
        #pragma unroll
        for (int e = 0; e < 8; e++) Qs[n8 + e][c] = pv[e];
    }
    f32x4 acc[4][4] = {};           // O[n(4x16)][c(4x16)] for this wave's c-chunk
    int cc0 = wid * 64;
    int fq = wid * 2;               // this wave's two S fragments
    __syncthreads();

    for (int mt = 0; mt < 64; mt++) {
        int m0 = mt * 64;
        { // stage K tile (transposed)
            int c = t >> 3, m8 = (t & 7) * 8;
            uint4 v = *(const uint4*)&kb[(size_t)c * NN + m0 + m8];
            const ushort* pv = (const ushort*)&v;
            #pragma unroll
            for (int e = 0; e < 8; e++) Ks[m8 + e][c] = pv[e];
        }
        __syncthreads();
        // S = Q^T K (16 fragments split across 8 waves, 2 each)
        #pragma unroll
        for (int ff = 0; ff < 2; ff++) {
            int f = fq + ff, fm = f >> 2, fn = f & 3;
            f32x4 s = {};
            #pragma unroll
            for (int kk = 0; kk < 2; kk++) {
                union { short8 v; uint u[4]; } au, bu;
                int n = fm * 16 + (lane & 15);
                int m = fn * 16 + (lane & 15);
                int c0 = kk * 32 + (lane >> 4) * 8;
                #pragma unroll
                for (int p = 0; p < 4; p++) {
                    au.u[p] = *(const uint*)&Qs[n][c0 + 2 * p];
                    bu.u[p] = *(const uint*)&Ks[m][c0 + 2 * p];
                }
                s = __builtin_amdgcn_mfma_f32_16x16x32_bf16(au.v, bu.v, s, 0, 0, 0);
            }
            #pragma unroll
            for (int r = 0; r < 4; r++)
                Ss[fm * 16 + (lane >> 4) * 4 + r][fn * 16 + (lane & 15)] = s[r];
        }
        __syncthreads();
        // online softmax: 8 threads per row
        {
            int row = t >> 3, part = t & 7;
            float e8[8];
            float rm = -1e30f;
            #pragma unroll
            for (int e = 0; e < 8; e++) { e8[e] = Ss[row][part * 8 + e]; rm = fmaxf(rm, e8[e]); }
            rm = fmaxf(rm, __shfl_xor(rm, 1, 64));
            rm = fmaxf(rm, __shfl_xor(rm, 2, 64));
            rm = fmaxf(rm, __shfl_xor(rm, 4, 64));
            float mo = row_m[row];
            float mn = fmaxf(mo, rm);
            float sc = __expf(mo - mn);
            float ps = 0.f;
            ushort p8[8];
            #pragma unroll
            for (int e = 0; e < 8; e++) {
                float p = __expf(e8[e] - mn);
                p8[e] = f2bf(p); ps += p;
            }
            *(uint4*)&Ps[row][part * 8] = *(const uint4*)p8;
            ps += __shfl_xor(ps, 1, 64);
            ps += __shfl_xor(ps, 2, 64);
            ps += __shfl_xor(ps, 4, 64);
            if (part == 0) {
                row_l[row] = row_l[row] * sc + ps;
                row_m[row] = mn;
                row_scale[row] = sc;
            }
        }
        __syncthreads();
        // rescale O, then O += P * V (V read from global; L2-resident per-XCD)
        float scl[4][4];
        #pragma unroll
        for (int fm = 0; fm < 4; fm++)
            #pragma unroll
            for (int r = 0; r < 4; r++)
                scl[fm][r] = row_scale[fm * 16 + (lane >> 4) * 4 + r];
        #pragma unroll
        for (int fm = 0; fm < 4; fm++)
            #pragma unroll
            for (int fc = 0; fc < 4; fc++)
                #pragma unroll
                for (int r = 0; r < 4; r++)
                    acc[fm][fc][r] *= scl[fm][r];
        #pragma unroll
        for (int kk = 0; kk < 2; kk++) {
            short8 pa[4], pb[4];
            #pragma unroll
            for (int fm = 0; fm < 4; fm++)
                pa[fm] = *(const short8*)&Ps[fm * 16 + (lane & 15)][kk * 32 + (lane >> 4) * 8];
            #pragma unroll
            for (int fc = 0; fc < 4; fc++) {
                int c = cc0 + fc * 16 + (lane & 15);
                pb[fc] = *(const short8*)&vb[(size_t)c * NN + m0 + kk * 32 + (lane >> 4) * 8];
            }
            #pragma unroll
            for (int fm = 0; fm < 4; fm++)
                #pragma unroll
                for (int fc = 0; fc < 4; fc++)
                    acc[fm][fc] = __builtin_amdgcn_mfma_f32_16x16x32_bf16(pa[fm], pb[fc], acc[fm][fc], 0, 0, 0);
        }
    }

    // epilogue: O /= l, LayerNorm over n (the 64 w-positions), upsample 2x2 + residual
    float g = gamma_p[0];
    const float* xb2 = x + (size_t)b * CC * HH * WW;
    float* ob = out + (size_t)b * CC * HH * WW;
    float rl[4][4], lwv[4][4], lbv[4][4];
    #pragma unroll
    for (int fm = 0; fm < 4; fm++)
        #pragma unroll
        for (int r = 0; r < 4; r++) {
            int n = fm * 16 + (lane >> 4) * 4 + r;
            rl[fm][r] = 1.f / row_l[n];
            lwv[fm][r] = lnw[n]; lbv[fm][r] = lnb[n];
        }
    #pragma unroll
    for (int fc = 0; fc < 4; fc++) {
        int c = cc0 + fc * 16 + (lane & 15);
        float vv[4][4];
        float vsum = 0.f, vsq = 0.f;
        #pragma unroll
        for (int fm = 0; fm < 4; fm++)
            #pragma unroll
            for (int r = 0; r < 4; r++) {
                float v = acc[fm][fc][r] * rl[fm][r];
                vv[fm][r] = v; vsum += v; vsq += v * v;
            }
        vsum += __shfl_xor(vsum, 16, 64); vsum += __shfl_xor(vsum, 32, 64);
        vsq  += __shfl_xor(vsq,  16, 64); vsq  += __shfl_xor(vsq,  32, 64);
        float mu  = vsum * (1.f / 64.f);
        float var = vsq * (1.f / 64.f) - mu * mu;
        float inv = rsqrtf(var + EPSF);
        const float* xrow = xb2 + (size_t)c * HH * WW + (2 * h) * WW;
        float*       orow = ob  + (size_t)c * HH * WW + (2 * h) * WW;
        #pragma unroll
        for (int fm = 0; fm < 4; fm++) {
            int nbase = fm * 16 + (lane >> 4) * 4;
            float nv[4];
            #pragma unroll
            for (int r = 0; r < 4; r++)
                nv[r] = g * ((vv[fm][r] - mu) * inv * lwv[fm][r] + lbv[fm][r]);
            #pragma unroll
            for (int dh = 0; dh < 2; dh++) {
                float4 xv0 = *(const float4*)&xrow[dh * WW + 2 * nbase];
                float4 xv1 = *(const float4*)&xrow[dh * WW + 2 * nbase + 4];
                float4 o0, o1;
                o0.x = nv[0] + xv0.x; o0.y = nv[0] + xv0.y;
                o0.z = nv[1] + xv0.z; o0.w = nv[1] + xv0.w;
                o1.x = nv[2] + xv1.x; o1.y = nv[2] + xv1.y;
                o1.z = nv[3] + xv1.z; o1.w = nv[3] + xv1.w;
                *(float4*)&orow[dh * WW + 2 * nbase]     = o0;
                *(float4*)&orow[dh * WW + 2 * nbase + 4] = o1;
            }
        }
    }
}

// ---------------------------------------------------------------------------
extern "C" void kernel_launch(void* const* d_in, const int* in_sizes, int n_in,
                              void* d_out, int out_size, void* d_ws, size_t ws_size,
                              hipStream_t stream)
{
    (void)in_sizes; (void)n_in; (void)out_size; (void)ws_size;
    const float* x    = (const float*)d_in[0];
    const float* wq   = (const float*)d_in[1];
    const float* bq   = (const float*)d_in[2];
    const float* wk   = (const float*)d_in[3];
    const float* bk   = (const float*)d_in[4];
    const float* wv   = (const float*)d_in[5];
    const float* bv   = (const float*)d_in[6];
    const float* gam  = (const float*)d_in[7];
    const float* lniw = (const float*)d_in[8];
    const float* lnib = (const float*)d_in[9];
    const float* lnow = (const float*)d_in[10];
    const float* lnob = (const float*)d_in[11];
    float* out = (float*)d_out;

    char* ws = (char*)d_ws;
    // ws layout (bytes), all bf16:
    //   xn : [8][512][4096] = 33,554,432
    //   q  : [8][ 64][4096] =  4,194,304
    //   k  : [8][ 64][4096] =  4,194,304
    //   v  : [8][512][4096] = 33,554,432   (total ~75.5 MB)
    ushort* xn = (ushort*)(ws);
    ushort* q  = (ushort*)(ws + 33554432u);
    ushort* k  = (ushort*)(ws + 37748736u);
    ushort* v  = (ushort*)(ws + 41943040u);

    pool_ln_kernel<<<65536, 256, 0, stream>>>(x, lniw, lnib, xn);
    qkv_kernel<<<dim3(64, 10, 8), 256, 0, stream>>>(xn, wq, bq, wk, bk, wv, bv, q, k, v);
    attn_kernel<<<512, 512, 0, stream>>>(q, k, v, x, gam, lnow, lnob, out);
}

// Round 3
// 667.871 us; speedup vs baseline: 1.0019x; 1.0019x over previous
//
#include <hip/hip_runtime.h>
#include <hip/hip_bf16.h>
#include <stdint.h>

// Problem constants
#define BB 8
#define CC 512
#define HH 128
#define WW 128
#define HP 64
#define NN 4096
#define C8 64
#define EPSF 1e-5f

typedef __attribute__((ext_vector_type(8))) short short8;   // 8 bf16 (4 VGPRs)
typedef __attribute__((ext_vector_type(4))) float f32x4;    // MFMA accumulator

__device__ __forceinline__ float bf2f(ushort u) {
    union { uint i; float f; } x; x.i = ((uint)u) << 16; return x.f;
}
__device__ __forceinline__ ushort f2bf(float f) {  // RNE
    uint i = __float_as_uint(f);
    return (ushort)((i + 0x7FFFu + ((i >> 16) & 1u)) >> 16);
}

// ---------------------------------------------------------------------------
// Kernel 1: AvgPool2d(2) + LayerNorm over pooled width (64) -> xn bf16 [B][C][4096]
// ---------------------------------------------------------------------------
__global__ __launch_bounds__(256) void pool_ln_kernel(
    const float* __restrict__ x, const float* __restrict__ lw,
    const float* __restrict__ lb, ushort* __restrict__ xn)
{
    int wid = threadIdx.x >> 6, lane = threadIdx.x & 63;
    int row = blockIdx.x * 4 + wid;      // (b*512+c)*64 + h
    int h = row & 63;
    int bc = row >> 6;
    const float* r0 = x + ((size_t)bc * 128 + 2 * h) * 128;
    const float* r1 = r0 + 128;
    float2 a0 = ((const float2*)r0)[lane];
    float2 a1 = ((const float2*)r1)[lane];
    float p = 0.25f * (a0.x + a0.y + a1.x + a1.y);
    float s = p, sq = p * p;
    #pragma unroll
    for (int m = 1; m < 64; m <<= 1) {
        s  += __shfl_xor(s,  m, 64);
        sq += __shfl_xor(sq, m, 64);
    }
    float mu  = s * (1.f / 64.f);
    float var = sq * (1.f / 64.f) - mu * mu;
    float inv = rsqrtf(var + EPSF);
    float v = (p - mu) * inv * lw[lane] + lb[lane];
    xn[(size_t)bc * NN + h * 64 + lane] = f2bf(v);
}

// ---------------------------------------------------------------------------
// Kernel 2: QKV projection GEMM (unchanged from passing version)
// ---------------------------------------------------------------------------
__global__ __launch_bounds__(256) void qkv_kernel(
    const ushort* __restrict__ xn,
    const float* __restrict__ wq, const float* __restrict__ bq,
    const float* __restrict__ wk, const float* __restrict__ bk,
    const float* __restrict__ wv, const float* __restrict__ bv,
    ushort* __restrict__ qo, ushort* __restrict__ ko, ushort* __restrict__ vo)
{
    __shared__ __align__(16) ushort As[64][40];
    __shared__ __align__(16) ushort Bs[64][66];
    int b = blockIdx.z, mt = blockIdx.y;
    int n0 = blockIdx.x * 64;
    const float* W; const float* bias; ushort* outp;
    if (mt == 0)      { W = wq;                               bias = bq;              outp = qo + (size_t)b * C8 * NN; }
    else if (mt == 1) { W = wk;                               bias = bk;              outp = ko + (size_t)b * C8 * NN; }
    else              { W = wv + (size_t)(mt - 2) * 64 * 512; bias = bv + (mt - 2) * 64;
                        outp = vo + (size_t)b * CC * NN + (size_t)(mt - 2) * 64 * NN; }
    const ushort* xb = xn + (size_t)b * CC * NN;
    int t = threadIdx.x;
    int lane = t & 63, wid = t >> 6;
    int wm = wid >> 1, wn = wid & 1;
    f32x4 acc[2][2] = {};

    for (int kc = 0; kc < 512; kc += 32) {
        {
            int row = t >> 2, k8 = (t & 3) * 8;
            const float* wp_ = &W[row * 512 + kc + k8];
            float4 f0 = *(const float4*)wp_;
            float4 f1 = *(const float4*)(wp_ + 4);
            ushort tmp[8] = { f2bf(f0.x), f2bf(f0.y), f2bf(f0.z), f2bf(f0.w),
                              f2bf(f1.x), f2bf(f1.y), f2bf(f1.z), f2bf(f1.w) };
            *(uint4*)&As[row][k8] = *(const uint4*)tmp;
        }
        {
            int c = t >> 3, n8 = (t & 7) * 8;
            uint4 v = *(const uint4*)&xb[(size_t)(kc + c) * NN + n0 + n8];
            const ushort* pv = (const ushort*)&v;
            #pragma unroll
            for (int e = 0; e < 8; e++) Bs[n8 + e][c] = pv[e];
        }
        __syncthreads();
        short8 a[2];
        #pragma unroll
        for (int fm = 0; fm < 2; fm++)
            a[fm] = *(const short8*)&As[wm * 32 + fm * 16 + (lane & 15)][(lane >> 4) * 8];
        short8 bb[2];
        #pragma unroll
        for (int fn = 0; fn < 2; fn++) {
            int col = wn * 32 + fn * 16 + (lane & 15);
            union { short8 v; uint u[4]; } bu;
            int c0 = (lane >> 4) * 8;
            #pragma unroll
            for (int p = 0; p < 4; p++)
                bu.u[p] = *(const uint*)&Bs[col][c0 + 2 * p];
            bb[fn] = bu.v;
        }
        #pragma unroll
        for (int fm = 0; fm < 2; fm++)
            #pragma unroll
            for (int fn = 0; fn < 2; fn++)
                acc[fm][fn] = __builtin_amdgcn_mfma_f32_16x16x32_bf16(a[fm], bb[fn], acc[fm][fn], 0, 0, 0);
        __syncthreads();
    }
    #pragma unroll
    for (int fm = 0; fm < 2; fm++) {
        #pragma unroll
        for (int fn = 0; fn < 2; fn++) {
            int col = n0 + wn * 32 + fn * 16 + (lane & 15);
            #pragma unroll
            for (int r = 0; r < 4; r++) {
                int orow = wm * 32 + fm * 16 + (lane >> 4) * 4 + r;
                outp[(size_t)orow * NN + col] = f2bf(acc[fm][fn][r] + bias[orow]);
            }
        }
    }
}

// ---------------------------------------------------------------------------
// Kernel 3: fused flash attention + out-LN + 2x nearest upsample + residual.
// KVBLK=128, subtiled LDS + ds_read_b64_tr_b16 fragments, 2 barriers/iter.
// ---------------------------------------------------------------------------
__global__ __launch_bounds__(512, 4) void attn_kernel(
    const ushort* __restrict__ qg, const ushort* __restrict__ kg,
    const ushort* __restrict__ vg, const float* __restrict__ x,
    const float* __restrict__ gamma_p,
    const float* __restrict__ lnw_g, const float* __restrict__ lnb_g,
    float* __restrict__ out)
{
    // Qs/Ks: subtiled [sub16][c][16] so staging is contiguous uint4 writes and
    // fragments come from ds_read_b64_tr_b16 (A and B share the c-permutation).
    __shared__ __align__(16) ushort Qs[4][64][16];   // 8 KB
    __shared__ __align__(16) ushort Ks[8][64][16];   // 16 KB
    __shared__ __align__(16) float  Ss[64][132];     // 33 KB  scores f32
    __shared__ __align__(16) ushort Ps[64][136];     // 17 KB  P bf16
    __shared__ float row_m[64], row_l[64], row_scale[64];
    __shared__ float lnw[64], lnb[64];

    int bid = blockIdx.x;
    int b = bid & 7;          // one batch per XCD slot (K/V L2 locality)
    int h = bid >> 3;
    int t = threadIdx.x, wid = t >> 6, lane = t & 63;
    const ushort* qb = qg + (size_t)b * C8 * NN;
    const ushort* kb = kg + (size_t)b * C8 * NN;
    const ushort* vb = vg + (size_t)b * CC * NN;

    if (t < 64) {
        row_m[t] = -1e30f; row_l[t] = 0.f;
        lnw[t] = lnw_g[t]; lnb[t] = lnb_g[t];
    }

    // stage Q tile + K tile 0 (contiguous writes into subtiled layout)
    int sc_ = t >> 3, sm8 = (t & 7) * 8;
    {
        uint4 qv = *(const uint4*)&qb[(size_t)sc_ * NN + h * 64 + sm8];
        *(uint4*)&Qs[sm8 >> 4][sc_][sm8 & 15] = qv;
        uint4 k0 = *(const uint4*)&kb[(size_t)sc_ * NN + sm8];
        uint4 k1 = *(const uint4*)&kb[(size_t)sc_ * NN + 64 + sm8];
        *(uint4*)&Ks[sm8 >> 4][sc_][sm8 & 15] = k0;
        *(uint4*)&Ks[(sm8 + 64) >> 4][sc_][sm8 & 15] = k1;
    }
    __syncthreads();

    int fmw = wid >> 1;            // this wave's S row-fragment (n block)
    int fnb = (wid & 1) * 4;       // first of this wave's 4 S col-fragments
    uint trofs = 2u * ((uint)(lane & 15) + (((uint)lane >> 4) << 6));

    // load this wave's Q A-fragments once (kk = 0,1)
    short8 qf[2];
    {
        uint qaddr = (uint)(uintptr_t)&Qs[fmw][0][0] + trofs;
        union { short8 v; unsigned long long u[2]; } q0, q1;
        asm volatile("ds_read_b64_tr_b16 %0, %4\n"
                     "ds_read_b64_tr_b16 %1, %4 offset:512\n"
                     "ds_read_b64_tr_b16 %2, %4 offset:1024\n"
                     "ds_read_b64_tr_b16 %3, %4 offset:1536"
                     : "=v"(q0.u[0]), "=v"(q0.u[1]), "=v"(q1.u[0]), "=v"(q1.u[1])
                     : "v"(qaddr));
        asm volatile("s_waitcnt lgkmcnt(0)" ::: "memory");
        __builtin_amdgcn_sched_barrier(0);
        qf[0] = q0.v; qf[1] = q1.v;
    }

    f32x4 acc[4][4] = {};
    int cc0 = wid * 64;

    for (int mt = 0; mt < 32; mt++) {
        int m0 = mt * 128;
        int m0n = ((mt + 1) & 31) * 128;   // wrap on last iter (data unused)
        // issue next K-tile global loads early (latency hides under QK+softmax)
        uint4 k0 = *(const uint4*)&kb[(size_t)sc_ * NN + m0n + sm8];
        uint4 k1 = *(const uint4*)&kb[(size_t)sc_ * NN + m0n + 64 + sm8];

        // ---- QK: 4 col-frags in 2 pairs (keeps VGPR pressure low) ----
        #pragma unroll
        for (int fp = 0; fp < 2; fp++) {
            union { short8 v; unsigned long long u[2]; } ka[2], kb2[2];
            uint a0 = (uint)(uintptr_t)&Ks[fnb + fp * 2][0][0] + trofs;
            uint a1 = (uint)(uintptr_t)&Ks[fnb + fp * 2 + 1][0][0] + trofs;
            asm volatile("ds_read_b64_tr_b16 %0, %4\n"
                         "ds_read_b64_tr_b16 %1, %4 offset:512\n"
                         "ds_read_b64_tr_b16 %2, %4 offset:1024\n"
                         "ds_read_b64_tr_b16 %3, %4 offset:1536"
                         : "=v"(ka[0].u[0]), "=v"(ka[0].u[1]), "=v"(ka[1].u[0]), "=v"(ka[1].u[1])
                         : "v"(a0));
            asm volatile("ds_read_b64_tr_b16 %0, %4\n"
                         "ds_read_b64_tr_b16 %1, %4 offset:512\n"
                         "ds_read_b64_tr_b16 %2, %4 offset:1024\n"
                         "ds_read_b64_tr_b16 %3, %4 offset:1536"
                         : "=v"(kb2[0].u[0]), "=v"(kb2[0].u[1]), "=v"(kb2[1].u[0]), "=v"(kb2[1].u[1])
                         : "v"(a1));
            asm volatile("s_waitcnt lgkmcnt(0)" ::: "memory");
            __builtin_amdgcn_sched_barrier(0);
            f32x4 s0 = {}, s1 = {};
            s0 = __builtin_amdgcn_mfma_f32_16x16x32_bf16(qf[0], ka[0].v,  s0, 0, 0, 0);
            s0 = __builtin_amdgcn_mfma_f32_16x16x32_bf16(qf[1], ka[1].v,  s0, 0, 0, 0);
            s1 = __builtin_amdgcn_mfma_f32_16x16x32_bf16(qf[0], kb2[0].v, s1, 0, 0, 0);
            s1 = __builtin_amdgcn_mfma_f32_16x16x32_bf16(qf[1], kb2[1].v, s1, 0, 0, 0);
            int rbase = fmw * 16 + (lane >> 4) * 4;
            int c0 = (fnb + fp * 2) * 16 + (lane & 15);
            #pragma unroll
            for (int r = 0; r < 4; r++) {
                Ss[rbase + r][c0]      = s0[r];
                Ss[rbase + r][c0 + 16] = s1[r];
            }
        }
        __syncthreads();   // bar1: Ss ready; all K tr-reads done

        // stage next K tile (Ks free: QK reads drained at bar1)
        *(uint4*)&Ks[sm8 >> 4][sc_][sm8 & 15] = k0;
        *(uint4*)&Ks[(sm8 + 64) >> 4][sc_][sm8 & 15] = k1;

        // ---- online softmax: 8 threads per row, 16 cols each ----
        {
            int row = t >> 3, part = t & 7;
            union { float4 f4[4]; float f[16]; } sv;
            #pragma unroll
            for (int i = 0; i < 4; i++) sv.f4[i] = *(const float4*)&Ss[row][part * 16 + i * 4];
            float rm = sv.f[0];
            #pragma unroll
            for (int i = 1; i < 16; i++) rm = fmaxf(rm, sv.f[i]);
            rm = fmaxf(rm, __shfl_xor(rm, 1, 64));
            rm = fmaxf(rm, __shfl_xor(rm, 2, 64));
            rm = fmaxf(rm, __shfl_xor(rm, 4, 64));
            float mo = row_m[row];
            float mnv = fmaxf(mo, rm);
            float scv = __expf(mo - mnv);
            float ps = 0.f;
            union { ushort s[16]; uint4 q[2]; } pk;
            #pragma unroll
            for (int i = 0; i < 16; i++) {
                float p = __expf(sv.f[i] - mnv);
                pk.s[i] = f2bf(p); ps += p;
            }
            *(uint4*)&Ps[row][part * 16]     = pk.q[0];
            *(uint4*)&Ps[row][part * 16 + 8] = pk.q[1];
            ps += __shfl_xor(ps, 1, 64);
            ps += __shfl_xor(ps, 2, 64);
            ps += __shfl_xor(ps, 4, 64);
            if (part == 0) {
                row_l[row] = row_l[row] * scv + ps;
                row_m[row] = mnv;
                row_scale[row] = scv;
            }
        }
        __syncthreads();   // bar2: Ps + stats + next Ks ready

        // ---- rescale O, then O += P * V (V from global; L2-resident) ----
        float scl[4][4];
        #pragma unroll
        for (int f = 0; f < 4; f++)
            #pragma unroll
            for (int r = 0; r < 4; r++)
                scl[f][r] = row_scale[f * 16 + (lane >> 4) * 4 + r];
        #pragma unroll
        for (int f = 0; f < 4; f++)
            #pragma unroll
            for (int g = 0; g < 4; g++)
                #pragma unroll
                for (int r = 0; r < 4; r++)
                    acc[f][g][r] *= scl[f][r];
        #pragma unroll
        for (int ks = 0; ks < 4; ks++) {
            short8 pa[4];
            #pragma unroll
            for (int f = 0; f < 4; f++)
                pa[f] = *(const short8*)&Ps[f * 16 + (lane & 15)][ks * 32 + (lane >> 4) * 8];
            #pragma unroll
            for (int g = 0; g < 4; g++) {
                short8 pb = *(const short8*)&vb[(size_t)(cc0 + g * 16 + (lane & 15)) * NN
                                                + m0 + ks * 32 + (lane >> 4) * 8];
                #pragma unroll
                for (int f = 0; f < 4; f++)
                    acc[f][g] = __builtin_amdgcn_mfma_f32_16x16x32_bf16(pa[f], pb, acc[f][g], 0, 0, 0);
            }
        }
    }

    // epilogue: O /= l, LayerNorm over n (64 w's), 2x2 upsample + residual
    float g = gamma_p[0];
    const float* xb2 = x + (size_t)b * CC * HH * WW;
    float* ob = out + (size_t)b * CC * HH * WW;
    float rl[4][4], lwv[4][4], lbv[4][4];
    #pragma unroll
    for (int fm = 0; fm < 4; fm++)
        #pragma unroll
        for (int r = 0; r < 4; r++) {
            int n = fm * 16 + (lane >> 4) * 4 + r;
            rl[fm][r] = 1.f / row_l[n];
            lwv[fm][r] = lnw[n]; lbv[fm][r] = lnb[n];
        }
    #pragma unroll
    for (int fc = 0; fc < 4; fc++) {
        int c = cc0 + fc * 16 + (lane & 15);
        float vv[4][4];
        float vsum = 0.f, vsq = 0.f;
        #pragma unroll
        for (int fm = 0; fm < 4; fm++)
            #pragma unroll
            for (int r = 0; r < 4; r++) {
                float v = acc[fm][fc][r] * rl[fm][r];
                vv[fm][r] = v; vsum += v; vsq += v * v;
            }
        vsum += __shfl_xor(vsum, 16, 64); vsum += __shfl_xor(vsum, 32, 64);
        vsq  += __shfl_xor(vsq,  16, 64); vsq  += __shfl_xor(vsq,  32, 64);
        float mu  = vsum * (1.f / 64.f);
        float var = vsq * (1.f / 64.f) - mu * mu;
        float inv = rsqrtf(var + EPSF);
        const float* xrow = xb2 + (size_t)c * HH * WW + (2 * h) * WW;
        float*       orow = ob  + (size_t)c * HH * WW + (2 * h) * WW;
        #pragma unroll
        for (int fm = 0; fm < 4; fm++) {
            int nbase = fm * 16 + (lane >> 4) * 4;
            float nv[4];
            #pragma unroll
            for (int r = 0; r < 4; r++)
                nv[r] = g * ((vv[fm][r] - mu) * inv * lwv[fm][r] + lbv[fm][r]);
            #pragma unroll
            for (int dh = 0; dh < 2; dh++) {
                float4 xv0 = *(const float4*)&xrow[dh * WW + 2 * nbase];
                float4 xv1 = *(const float4*)&xrow[dh * WW + 2 * nbase + 4];
                float4 o0, o1;
                o0.x = nv[0] + xv0.x; o0.y = nv[0] + xv0.y;
                o0.z = nv[1] + xv0.z; o0.w = nv[1] + xv0.w;
                o1.x = nv[2] + xv1.x; o1.y = nv[2] + xv1.y;
                o1.z = nv[3] + xv1.z; o1.w = nv[3] + xv1.w;
                *(float4*)&orow[dh * WW + 2 * nbase]     = o0;
                *(float4*)&orow[dh * WW + 2 * nbase + 4] = o1;
            }
        }
    }
}

// ---------------------------------------------------------------------------
extern "C" void kernel_launch(void* const* d_in, const int* in_sizes, int n_in,
                              void* d_out, int out_size, void* d_ws, size_t ws_size,
                              hipStream_t stream)
{
    (void)in_sizes; (void)n_in; (void)out_size; (void)ws_size;
    const float* x    = (const float*)d_in[0];
    const float* wq   = (const float*)d_in[1];
    const float* bq   = (const float*)d_in[2];
    const float* wk   = (const float*)d_in[3];
    const float* bk   = (const float*)d_in[4];
    const float* wv   = (const float*)d_in[5];
    const float* bv   = (const float*)d_in[6];
    const float* gam  = (const float*)d_in[7];
    const float* lniw = (const float*)d_in[8];
    const float* lnib = (const float*)d_in[9];
    const float* lnow = (const float*)d_in[10];
    const float* lnob = (const float*)d_in[11];
    float* out = (float*)d_out;

    char* ws = (char*)d_ws;
    ushort* xn = (ushort*)(ws);
    ushort* q  = (ushort*)(ws + 33554432u);
    ushort* k  = (ushort*)(ws + 37748736u);
    ushort* v  = (ushort*)(ws + 41943040u);

    pool_ln_kernel<<<65536, 256, 0, stream>>>(x, lniw, lnib, xn);
    qkv_kernel<<<dim3(64, 10, 8), 256, 0, stream>>>(xn, wq, bq, wk, bk, wv, bv, q, k, v);
    attn_kernel<<<512, 512, 0, stream>>>(q, k, v, x, gam, lnow, lnob, out);
}